// Round 6
// baseline (570.756 us; speedup 1.0000x reference)
//
#include <hip/hip_runtime.h>
#include <hip/hip_bf16.h>

// Problem constants (from the reference)
#define N_IN_SZ   (721 * 1440)   // 1,038,240
#define N_ROWS    (361 * 720)    //   259,920 output cells
#define BC        64             // B*C = 4*16
#define NBKT      ((N_ROWS + 63) / 64)   // 4062 row-buckets of 64 rows
#define NSLICE    64                      // column slices (16,384 cols = 2 MB of xt)
#define SLICE_SHIFT 14
#define NCELL     (NBKT * NSLICE)        // 259,968 (bucket, slice) cells

// ---------------- exact two-level CSR: count / scan / scatter ----------------

__global__ void count_kernel(const int* __restrict__ rows, const int* __restrict__ cols,
                             int* __restrict__ cellcnt, int nnz) {
    int k = blockIdx.x * blockDim.x + threadIdx.x;
    if (k < nnz) {
        const int cell = (rows[k] >> 6) * NSLICE + (cols[k] >> SLICE_SHIFT);
        atomicAdd(&cellcnt[cell], 1);
    }
}

__global__ void scan1_kernel(const int* __restrict__ counts, int* __restrict__ excl,
                             int* __restrict__ aux, int n) {
    __shared__ int sdata[256];
    const int t = threadIdx.x;
    const int base = blockIdx.x * 1024 + t * 4;
    int v[4];
    #pragma unroll
    for (int j = 0; j < 4; ++j) {
        int idx = base + j;
        v[j] = (idx < n) ? counts[idx] : 0;
    }
    int tsum = v[0] + v[1] + v[2] + v[3];
    sdata[t] = tsum;
    __syncthreads();
    for (int off = 1; off < 256; off <<= 1) {
        int xv = (t >= off) ? sdata[t - off] : 0;
        __syncthreads();
        sdata[t] += xv;
        __syncthreads();
    }
    int run = sdata[t] - tsum;
    if (t == 255) aux[blockIdx.x] = sdata[255];
    #pragma unroll
    for (int j = 0; j < 4; ++j) {
        int idx = base + j;
        if (idx < n) excl[idx] = run;
        run += v[j];
    }
}

__global__ void scan2_kernel(int* __restrict__ aux, int n2) {
    __shared__ int sdata[256];
    const int t = threadIdx.x;
    int a = (t < n2) ? aux[t] : 0;
    sdata[t] = a;
    __syncthreads();
    for (int off = 1; off < 256; off <<= 1) {
        int xv = (t >= off) ? sdata[t - off] : 0;
        __syncthreads();
        sdata[t] += xv;
        __syncthreads();
    }
    if (t < n2) aux[t] = sdata[t] - a;
}

__global__ void scan3_kernel(int* __restrict__ cell_ptr, const int* __restrict__ aux,
                             int n, int nnz) {
    const int add = aux[blockIdx.x];
    const int base = blockIdx.x * 1024 + threadIdx.x * 4;
    #pragma unroll
    for (int j = 0; j < 4; ++j) {
        int idx = base + j;
        if (idx < n) cell_ptr[idx] += add;
    }
    if (blockIdx.x == 0 && threadIdx.x == 0) cell_ptr[n] = nnz;
}

// entry = { col | (row&63)<<20 , weight_bits } ; col < 2^20, rlo 6 bits.
__global__ void scatter_kernel(const int* __restrict__ rows, const int* __restrict__ cols,
                               const float* __restrict__ S,
                               const int* __restrict__ cell_ptr, int* __restrict__ cursor,
                               int2* __restrict__ entries, int nnz) {
    int k = blockIdx.x * blockDim.x + threadIdx.x;
    if (k < nnz) {
        const int r = rows[k];
        const int c = cols[k];
        const int cell = (r >> 6) * NSLICE + (c >> SLICE_SHIFT);
        const int p = cell_ptr[cell] + atomicAdd(&cursor[cell], 1);
        entries[p] = make_int2(c | ((r & 63) << 20), __float_as_int(S[k]));
    }
}

// ---------------- x transpose: [64][N_IN] f32 -> [N_IN][64] bf16 ----------------

__global__ void transpose_kernel(const float* __restrict__ x, __hip_bfloat16* __restrict__ xt) {
    __shared__ float tile[64][65];
    const int c0 = blockIdx.x * 64;
    const int tx = threadIdx.x & 63;
    const int ty = threadIdx.x >> 6;   // 0..3
    const int cr = c0 + tx;
    #pragma unroll
    for (int r = 0; r < 64; r += 4) {
        const int bc = r + ty;
        tile[tx][bc] = (cr < N_IN_SZ) ? x[(size_t)bc * N_IN_SZ + cr] : 0.f;
    }
    __syncthreads();
    #pragma unroll
    for (int r = 0; r < 64; r += 4) {
        const int cy = r + ty;
        const int c = c0 + cy;
        if (c < N_IN_SZ) xt[(size_t)c * 64 + tx] = __float2bfloat16(tile[cy][tx]);
    }
}

// ---------------- gather: block = 64-row bucket x 64 bc, entries col-sorted ----------------
// 4 waves chew the bucket's (column-ordered) entry list in interleaved batches of 8;
// lane = bc; accumulate via LDS workgroup-scope float add into tile[bc][rlo];
// coalesced float4 writeout. Col-ordering phase-locks blocks onto the same xt slices.

__global__ void gather_kernel(const __hip_bfloat16* __restrict__ xt,
                              const int* __restrict__ cell_ptr,
                              const int2* __restrict__ entries,
                              float* __restrict__ y) {
    __shared__ float tile[64][65];
    const int b = blockIdx.x;
    const int lane = threadIdx.x & 63;
    const int wave = threadIdx.x >> 6;
    const int base = b * 64;

    for (int i = threadIdx.x; i < 64 * 65; i += 256) ((float*)tile)[i] = 0.f;
    __syncthreads();

    const int s = cell_ptr[b * NSLICE];
    const int e = cell_ptr[(b + 1) * NSLICE];

    for (int t = s + wave * 8; t < e; t += 32) {
        int n = e - t; if (n > 8) n = 8;
        int2 E[8];
        #pragma unroll
        for (int j = 0; j < 8; ++j) if (j < n) E[j] = entries[t + j];   // uniform broadcast
        float xv[8];
        #pragma unroll
        for (int j = 0; j < 8; ++j) if (j < n)
            xv[j] = __bfloat162float(xt[(size_t)(E[j].x & 0xFFFFF) * 64 + lane]);
        #pragma unroll
        for (int j = 0; j < 8; ++j) if (j < n)
            __hip_atomic_fetch_add(&tile[lane][E[j].x >> 20],
                                   __int_as_float(E[j].y) * xv[j],
                                   __ATOMIC_RELAXED, __HIP_MEMORY_SCOPE_WORKGROUP);
    }
    __syncthreads();

    // writeout: 1024 float4 tasks = 64 bc x 16 quads; 4 per thread
    #pragma unroll
    for (int j = 0; j < 4; ++j) {
        const int task = j * 256 + threadIdx.x;
        const int bc = task >> 4;
        const int r0 = (task & 15) * 4;
        const int i0 = base + r0;
        float4 v = make_float4(tile[bc][r0], tile[bc][r0 + 1],
                               tile[bc][r0 + 2], tile[bc][r0 + 3]);
        float* yp = y + (size_t)bc * N_ROWS;
        if (i0 + 3 < N_ROWS) {
            *(float4*)&yp[i0] = v;
        } else {
            if (i0 + 0 < N_ROWS) yp[i0 + 0] = v.x;
            if (i0 + 1 < N_ROWS) yp[i0 + 1] = v.y;
            if (i0 + 2 < N_ROWS) yp[i0 + 2] = v.z;
            if (i0 + 3 < N_ROWS) yp[i0 + 3] = v.w;
        }
    }
}

// ---------------- last-resort atomic COO ----------------

__global__ void regrid_coo_kernel(const float* __restrict__ x, const float* __restrict__ S,
                                  const int* __restrict__ rows, const int* __restrict__ cols,
                                  float* __restrict__ y, int nnz) {
    const int bc = blockIdx.y;
    const float* __restrict__ xp = x + (size_t)bc * N_IN_SZ;
    float* __restrict__ yp = y + (size_t)bc * N_ROWS;
    int k = blockIdx.x * blockDim.x + threadIdx.x;
    const int stride = gridDim.x * blockDim.x;
    for (; k < nnz; k += stride) {
        atomicAdd(&yp[rows[k]], S[k] * xp[cols[k]]);
    }
}

extern "C" void kernel_launch(void* const* d_in, const int* in_sizes, int n_in,
                              void* d_out, int out_size, void* d_ws, size_t ws_size,
                              hipStream_t stream) {
    const float* x    = (const float*)d_in[0];
    const float* S    = (const float*)d_in[1];
    const int*   rows = (const int*)d_in[2];
    const int*   cols = (const int*)d_in[3];
    float*       y    = (float*)d_out;
    const int nnz = in_sizes[1];

    // Workspace layout (256B-aligned chunks)
    const size_t SZ_CELLCNT = ((size_t)NCELL * 4 + 255) & ~255ULL;        // 1.04 MB
    const size_t SZ_CURSOR  = SZ_CELLCNT;                                  // 1.04 MB
    const size_t SZ_CPTR    = ((size_t)(NCELL + 1) * 4 + 255) & ~255ULL;   // 1.04 MB
    const size_t SZ_AUX     = 1024;
    const size_t SZ_ENT     = ((size_t)nnz * 8 + 255) & ~255ULL;           // 8.4 MB
    const size_t SZ_XT      = ((size_t)N_IN_SZ * BC * 2 + 255) & ~255ULL;  // 133 MB
    const size_t NEED = SZ_CELLCNT + SZ_CURSOR + SZ_CPTR + SZ_AUX + SZ_ENT + SZ_XT;

    if (ws_size < NEED) {
        hipMemsetAsync(d_out, 0, (size_t)out_size * sizeof(float), stream);
        dim3 grid(1024, BC, 1);
        regrid_coo_kernel<<<grid, 256, 0, stream>>>(x, S, rows, cols, y, nnz);
        return;
    }

    char* w = (char*)d_ws;
    int*  cellcnt  = (int*)(w);
    int*  cursor   = (int*)(w + SZ_CELLCNT);
    int*  cell_ptr = (int*)(w + SZ_CELLCNT + SZ_CURSOR);
    int*  aux      = (int*)(w + SZ_CELLCNT + SZ_CURSOR + SZ_CPTR);
    int2* entries  = (int2*)(w + SZ_CELLCNT + SZ_CURSOR + SZ_CPTR + SZ_AUX);
    __hip_bfloat16* xt = (__hip_bfloat16*)(w + SZ_CELLCNT + SZ_CURSOR + SZ_CPTR + SZ_AUX + SZ_ENT);

    // zero cell counts + cursors in one memset (contiguous)
    hipMemsetAsync(cellcnt, 0, SZ_CELLCNT + SZ_CURSOR, stream);

    const int tBlocks = (N_IN_SZ + 63) / 64;  // 16,223
    transpose_kernel<<<tBlocks, 256, 0, stream>>>(x, xt);

    const int nnzBlocks  = (nnz + 255) / 256;
    const int scanBlocks = (NCELL + 1023) / 1024;  // 254

    count_kernel<<<nnzBlocks, 256, 0, stream>>>(rows, cols, cellcnt, nnz);
    scan1_kernel<<<scanBlocks, 256, 0, stream>>>(cellcnt, cell_ptr, aux, NCELL);
    scan2_kernel<<<1, 256, 0, stream>>>(aux, scanBlocks);
    scan3_kernel<<<scanBlocks, 256, 0, stream>>>(cell_ptr, aux, NCELL, nnz);
    scatter_kernel<<<nnzBlocks, 256, 0, stream>>>(rows, cols, S, cell_ptr, cursor, entries, nnz);

    gather_kernel<<<NBKT, 256, 0, stream>>>(xt, cell_ptr, entries, y);
}

// Round 7
// 295.798 us; speedup vs baseline: 1.9295x; 1.9295x over previous
//
#include <hip/hip_runtime.h>
#include <hip/hip_bf16.h>

// Problem constants (from the reference)
#define N_IN_SZ   (721 * 1440)   // 1,038,240
#define N_ROWS    (361 * 720)    //   259,920 output cells
#define BC        64             // B*C = 4*16
#define ROW_CAP   16             // padded entries per row (lambda=4.03)
#define OF_CAP    4096

// ---------------- fused prep: scatter (first blocks) || transpose ----------------
// scatter: rows/cols/S -> per-row padded buckets epad[r*ROW_CAP + slot]
// transpose: x [64][N_IN] f32 -> xt [N_IN][64] bf16

__global__ void prep_kernel(const float* __restrict__ x,
                            const int* __restrict__ rows, const int* __restrict__ cols,
                            const float* __restrict__ S,
                            int* __restrict__ cursor, int2* __restrict__ epad,
                            int* __restrict__ of_count, int4* __restrict__ of_list,
                            __hip_bfloat16* __restrict__ xt,
                            int nnz, int scBlocks) {
    __shared__ float tile[64][65];
    if ((int)blockIdx.x < scBlocks) {
        // ---- scatter part ----
        const int k = blockIdx.x * blockDim.x + threadIdx.x;
        if (k < nnz) {
            const int r = rows[k];
            const int slot = atomicAdd(&cursor[r], 1);
            if (slot < ROW_CAP) {
                epad[(size_t)r * ROW_CAP + slot] = make_int2(cols[k], __float_as_int(S[k]));
            } else {
                int o = atomicAdd(of_count, 1);
                if (o < OF_CAP) of_list[o] = make_int4(r, cols[k], __float_as_int(S[k]), 0);
            }
        }
        return;
    }
    // ---- transpose part ----
    const int c0 = (blockIdx.x - scBlocks) * 64;
    const int tx = threadIdx.x & 63;
    const int ty = threadIdx.x >> 6;   // 0..3
    const int cr = c0 + tx;
    #pragma unroll
    for (int r = 0; r < 64; r += 4) {
        const int bc = r + ty;
        tile[tx][bc] = (cr < N_IN_SZ) ? x[(size_t)bc * N_IN_SZ + cr] : 0.f;
    }
    __syncthreads();
    #pragma unroll
    for (int r = 0; r < 64; r += 4) {
        const int cy = r + ty;
        const int c = c0 + cy;
        if (c < N_IN_SZ) xt[(size_t)c * 64 + tx] = __float2bfloat16(tile[cy][tx]);
    }
}

// ---------------- gather: block = 64 rows x 64 bc; wave owns 16 rows, ----------------
// processed as pairs (rr, rr+8) with batch-4 UNCONDITIONAL loads -> ~8 loads in flight.
// Register accumulation (no LDS atomics), LDS tile + coalesced float4 writeout.

__global__ void gather_kernel(const __hip_bfloat16* __restrict__ xt,
                              const int* __restrict__ cursor,
                              const int2* __restrict__ epad,
                              float* __restrict__ y) {
    __shared__ float tile[64][65];
    __shared__ int cnt[64];
    const int b = blockIdx.x;
    const int base = b * 64;
    const int lane = threadIdx.x & 63;
    const int wave = threadIdx.x >> 6;

    if (threadIdx.x < 64) {
        const int r = base + threadIdx.x;
        int c = (r < N_ROWS) ? cursor[r] : 0;
        cnt[threadIdx.x] = (c > ROW_CAP) ? ROW_CAP : c;
    }
    __syncthreads();

    for (int rr = 0; rr < 8; ++rr) {
        const int r0 = wave * 16 + rr;
        const int r1 = r0 + 8;
        const int c0 = cnt[r0];
        const int c1 = cnt[r1];
        const int2* __restrict__ e0 = epad + (size_t)(base + r0) * ROW_CAP;
        const int2* __restrict__ e1 = epad + (size_t)(base + r1) * ROW_CAP;
        float a0 = 0.f, a1 = 0.f;
        int t0 = 0, t1 = 0;
        while (t0 < c0 || t1 < c1) {
            const bool g0 = (t0 < c0), g1 = (t1 < c1);
            int2 E0[4], E1[4];
            // unconditional batch loads (always within the padded row: t+3 <= 15)
            #pragma unroll
            for (int j = 0; j < 4; ++j) E0[j] = g0 ? e0[t0 + j] : make_int2(0, 0);
            #pragma unroll
            for (int j = 0; j < 4; ++j) E1[j] = g1 ? e1[t1 + j] : make_int2(0, 0);
            float x0[4], x1[4];
            #pragma unroll
            for (int j = 0; j < 4; ++j) {
                const int col = (t0 + j < c0) ? E0[j].x : 0;     // mask garbage index
                x0[j] = __bfloat162float(xt[(size_t)col * 64 + lane]);
            }
            #pragma unroll
            for (int j = 0; j < 4; ++j) {
                const int col = (t1 + j < c1) ? E1[j].x : 0;
                x1[j] = __bfloat162float(xt[(size_t)col * 64 + lane]);
            }
            #pragma unroll
            for (int j = 0; j < 4; ++j) {
                const float w0 = (t0 + j < c0) ? __int_as_float(E0[j].y) : 0.f;
                a0 += w0 * x0[j];
            }
            #pragma unroll
            for (int j = 0; j < 4; ++j) {
                const float w1 = (t1 + j < c1) ? __int_as_float(E1[j].y) : 0.f;
                a1 += w1 * x1[j];
            }
            if (g0) t0 += 4;
            if (g1) t1 += 4;
        }
        tile[lane][r0] = a0;
        tile[lane][r1] = a1;
    }
    __syncthreads();

    // writeout: 1024 float4 tasks = 64 bc x 16 quads; 4 per thread
    #pragma unroll
    for (int j = 0; j < 4; ++j) {
        const int task = j * 256 + threadIdx.x;
        const int bc = task >> 4;
        const int r0 = (task & 15) * 4;
        const int i0 = base + r0;
        float4 v = make_float4(tile[bc][r0], tile[bc][r0 + 1],
                               tile[bc][r0 + 2], tile[bc][r0 + 3]);
        float* yp = y + (size_t)bc * N_ROWS;
        if (i0 + 3 < N_ROWS) {
            *(float4*)&yp[i0] = v;
        } else {
            if (i0 + 0 < N_ROWS) yp[i0 + 0] = v.x;
            if (i0 + 1 < N_ROWS) yp[i0 + 1] = v.y;
            if (i0 + 2 < N_ROWS) yp[i0 + 2] = v.z;
            if (i0 + 3 < N_ROWS) yp[i0 + 3] = v.w;
        }
    }
}

// ---------------- overflow cleanup (expected ~0 entries) ----------------

__global__ void cleanup_kernel(const int* __restrict__ of_count,
                               const int4* __restrict__ of_list,
                               const float* __restrict__ x, float* __restrict__ y) {
    int n = *of_count;
    if (n > OF_CAP) n = OF_CAP;
    const int total = n * 64;
    for (int t = blockIdx.x * blockDim.x + threadIdx.x; t < total;
         t += gridDim.x * blockDim.x) {
        const int e = t >> 6, bc = t & 63;
        const int4 E = of_list[e];
        atomicAdd(&y[(size_t)bc * N_ROWS + E.x],
                  __int_as_float(E.z) * x[(size_t)bc * N_IN_SZ + E.y]);
    }
}

// ---------------- last-resort atomic COO ----------------

__global__ void regrid_coo_kernel(const float* __restrict__ x, const float* __restrict__ S,
                                  const int* __restrict__ rows, const int* __restrict__ cols,
                                  float* __restrict__ y, int nnz) {
    const int bc = blockIdx.y;
    const float* __restrict__ xp = x + (size_t)bc * N_IN_SZ;
    float* __restrict__ yp = y + (size_t)bc * N_ROWS;
    int k = blockIdx.x * blockDim.x + threadIdx.x;
    const int stride = gridDim.x * blockDim.x;
    for (; k < nnz; k += stride) {
        atomicAdd(&yp[rows[k]], S[k] * xp[cols[k]]);
    }
}

extern "C" void kernel_launch(void* const* d_in, const int* in_sizes, int n_in,
                              void* d_out, int out_size, void* d_ws, size_t ws_size,
                              hipStream_t stream) {
    const float* x    = (const float*)d_in[0];
    const float* S    = (const float*)d_in[1];
    const int*   rows = (const int*)d_in[2];
    const int*   cols = (const int*)d_in[3];
    float*       y    = (float*)d_out;
    const int nnz = in_sizes[1];

    // Workspace layout (256B-aligned chunks)
    const size_t SZ_CURSOR = ((size_t)N_ROWS * 4 + 255) & ~255ULL;             // 1.04 MB
    const size_t SZ_OFCNT  = 256;
    const size_t SZ_OFLIST = ((size_t)OF_CAP * 16 + 255) & ~255ULL;            // 64 KB
    const size_t SZ_EPAD   = ((size_t)N_ROWS * ROW_CAP * 8 + 255) & ~255ULL;   // 33.3 MB
    const size_t SZ_XT     = ((size_t)N_IN_SZ * BC * 2 + 255) & ~255ULL;       // 133 MB
    const size_t NEED = SZ_CURSOR + SZ_OFCNT + SZ_OFLIST + SZ_EPAD + SZ_XT;

    if (ws_size < NEED) {
        hipMemsetAsync(d_out, 0, (size_t)out_size * sizeof(float), stream);
        dim3 grid(1024, BC, 1);
        regrid_coo_kernel<<<grid, 256, 0, stream>>>(x, S, rows, cols, y, nnz);
        return;
    }

    char* w = (char*)d_ws;
    int*  cursor   = (int*)(w);
    int*  of_count = (int*)(w + SZ_CURSOR);
    int4* of_list  = (int4*)(w + SZ_CURSOR + SZ_OFCNT);
    int2* epad     = (int2*)(w + SZ_CURSOR + SZ_OFCNT + SZ_OFLIST);
    __hip_bfloat16* xt = (__hip_bfloat16*)(w + SZ_CURSOR + SZ_OFCNT + SZ_OFLIST + SZ_EPAD);

    // zero cursors + overflow count in one memset (contiguous)
    hipMemsetAsync(cursor, 0, SZ_CURSOR + SZ_OFCNT, stream);

    const int scBlocks = (nnz + 255) / 256;           // 4096 scatter blocks (run first)
    const int tBlocks  = (N_IN_SZ + 63) / 64;         // 16,223 transpose blocks
    prep_kernel<<<scBlocks + tBlocks, 256, 0, stream>>>(x, rows, cols, S, cursor, epad,
                                                        of_count, of_list, xt, nnz, scBlocks);

    const int gBlocks = (N_ROWS + 63) / 64;           // 4,062
    gather_kernel<<<gBlocks, 256, 0, stream>>>(xt, cursor, epad, y);

    cleanup_kernel<<<16, 256, 0, stream>>>(of_count, of_list, x, y);
}

// Round 8
// 231.981 us; speedup vs baseline: 2.4604x; 1.2751x over previous
//
#include <hip/hip_runtime.h>
#include <hip/hip_bf16.h>

// Problem constants (from the reference)
#define N_IN_SZ   (721 * 1440)   // 1,038,240
#define N_ROWS    (361 * 720)    //   259,920 output cells
#define BC        64             // B*C = 4*16
#define ROW_CAP   16             // padded entries per row (lambda=4.03)
#define OF_CAP    4096

// ---------------- fused prep: scatter (every 5th block) || transpose ----------------
// scatter: rows/cols/S -> per-row padded buckets epad[r*ROW_CAP + slot]  (grid-stride)
// transpose: x [64][N_IN] f32 -> xt [N_IN][64] bf16, float4 loads / ushort4 stores

__global__ void prep_kernel(const float* __restrict__ x,
                            const int* __restrict__ rows, const int* __restrict__ cols,
                            const float* __restrict__ S,
                            int* __restrict__ cursor, int2* __restrict__ epad,
                            int* __restrict__ of_count, int4* __restrict__ of_list,
                            __hip_bfloat16* __restrict__ xt,
                            int nnz) {
    __shared__ float tile[64][65];   // [bc][colOff]
    const int bid = blockIdx.x;

    if ((bid % 5) == 4) {
        // ---- scatter part (interleaved through the dispatch) ----
        const int nsc = gridDim.x / 5;                 // # scatter blocks
        const int stride = nsc * 256;
        for (int k = (bid / 5) * 256 + threadIdx.x; k < nnz; k += stride) {
            const int r = rows[k];
            const int slot = atomicAdd(&cursor[r], 1);
            if (slot < ROW_CAP) {
                epad[(size_t)r * ROW_CAP + slot] = make_int2(cols[k], __float_as_int(S[k]));
            } else {
                int o = atomicAdd(of_count, 1);
                if (o < OF_CAP) of_list[o] = make_int4(r, cols[k], __float_as_int(S[k]), 0);
            }
        }
        return;
    }

    // ---- transpose part ----
    const int t_idx = bid - (bid + 1) / 5;
    const int c0 = t_idx * 64;
    if (c0 >= N_IN_SZ) return;
    const int lane = threadIdx.x & 63;
    const int wave = threadIdx.x >> 6;   // 0..3

    if (c0 + 64 <= N_IN_SZ) {
        // fast path: float4 loads, 4 bc-rows per wave per iter
        #pragma unroll
        for (int i = 0; i < 4; ++i) {
            const int bc = wave * 16 + i * 4 + (lane >> 4);
            const int cc = 4 * (lane & 15);
            const float4 v = *(const float4*)&x[(size_t)bc * N_IN_SZ + c0 + cc];
            tile[bc][cc + 0] = v.x;
            tile[bc][cc + 1] = v.y;
            tile[bc][cc + 2] = v.z;
            tile[bc][cc + 3] = v.w;
        }
    } else {
        // tail tile (one block): scalar guarded
        for (int e = threadIdx.x; e < 64 * 64; e += 256) {
            const int bc = e >> 6, cc = e & 63;
            const int c = c0 + cc;
            tile[bc][cc] = (c < N_IN_SZ) ? x[(size_t)bc * N_IN_SZ + c] : 0.f;
        }
    }
    __syncthreads();

    // store: ushort4 per lane (4 bc), 4 c-rows per wave per iter -> 512B/wave-instr
    #pragma unroll
    for (int i = 0; i < 4; ++i) {
        const int cl = wave * 16 + i * 4 + (lane >> 4);
        const int c = c0 + cl;
        if (c < N_IN_SZ) {
            const int bc4 = 4 * (lane & 15);
            ushort4 o;
            __hip_bfloat16 h0 = __float2bfloat16(tile[bc4 + 0][cl]);
            __hip_bfloat16 h1 = __float2bfloat16(tile[bc4 + 1][cl]);
            __hip_bfloat16 h2 = __float2bfloat16(tile[bc4 + 2][cl]);
            __hip_bfloat16 h3 = __float2bfloat16(tile[bc4 + 3][cl]);
            o.x = *(unsigned short*)&h0;
            o.y = *(unsigned short*)&h1;
            o.z = *(unsigned short*)&h2;
            o.w = *(unsigned short*)&h3;
            *(ushort4*)&xt[(size_t)c * 64 + bc4] = o;
        }
    }
}

// ---------------- gather: block = 64 rows x 64 bc; wave owns 16 rows, ----------------
// processed as pairs (rr, rr+8) with batch-4 UNCONDITIONAL loads -> ~8 loads in flight.
// Register accumulation (no LDS atomics), LDS tile + coalesced float4 writeout.

__global__ void gather_kernel(const __hip_bfloat16* __restrict__ xt,
                              const int* __restrict__ cursor,
                              const int2* __restrict__ epad,
                              float* __restrict__ y) {
    __shared__ float tile[64][65];
    __shared__ int cnt[64];
    const int b = blockIdx.x;
    const int base = b * 64;
    const int lane = threadIdx.x & 63;
    const int wave = threadIdx.x >> 6;

    if (threadIdx.x < 64) {
        const int r = base + threadIdx.x;
        int c = (r < N_ROWS) ? cursor[r] : 0;
        cnt[threadIdx.x] = (c > ROW_CAP) ? ROW_CAP : c;
    }
    __syncthreads();

    for (int rr = 0; rr < 8; ++rr) {
        const int r0 = wave * 16 + rr;
        const int r1 = r0 + 8;
        const int c0 = cnt[r0];
        const int c1 = cnt[r1];
        const int2* __restrict__ e0 = epad + (size_t)(base + r0) * ROW_CAP;
        const int2* __restrict__ e1 = epad + (size_t)(base + r1) * ROW_CAP;
        float a0 = 0.f, a1 = 0.f;
        int t0 = 0, t1 = 0;
        while (t0 < c0 || t1 < c1) {
            const bool g0 = (t0 < c0), g1 = (t1 < c1);
            int2 E0[4], E1[4];
            #pragma unroll
            for (int j = 0; j < 4; ++j) E0[j] = g0 ? e0[t0 + j] : make_int2(0, 0);
            #pragma unroll
            for (int j = 0; j < 4; ++j) E1[j] = g1 ? e1[t1 + j] : make_int2(0, 0);
            float x0[4], x1[4];
            #pragma unroll
            for (int j = 0; j < 4; ++j) {
                const int col = (t0 + j < c0) ? E0[j].x : 0;
                x0[j] = __bfloat162float(xt[(size_t)col * 64 + lane]);
            }
            #pragma unroll
            for (int j = 0; j < 4; ++j) {
                const int col = (t1 + j < c1) ? E1[j].x : 0;
                x1[j] = __bfloat162float(xt[(size_t)col * 64 + lane]);
            }
            #pragma unroll
            for (int j = 0; j < 4; ++j) {
                const float w0 = (t0 + j < c0) ? __int_as_float(E0[j].y) : 0.f;
                a0 += w0 * x0[j];
            }
            #pragma unroll
            for (int j = 0; j < 4; ++j) {
                const float w1 = (t1 + j < c1) ? __int_as_float(E1[j].y) : 0.f;
                a1 += w1 * x1[j];
            }
            if (g0) t0 += 4;
            if (g1) t1 += 4;
        }
        tile[lane][r0] = a0;
        tile[lane][r1] = a1;
    }
    __syncthreads();

    // writeout: 1024 float4 tasks = 64 bc x 16 quads; 4 per thread
    #pragma unroll
    for (int j = 0; j < 4; ++j) {
        const int task = j * 256 + threadIdx.x;
        const int bc = task >> 4;
        const int r0 = (task & 15) * 4;
        const int i0 = base + r0;
        float4 v = make_float4(tile[bc][r0], tile[bc][r0 + 1],
                               tile[bc][r0 + 2], tile[bc][r0 + 3]);
        float* yp = y + (size_t)bc * N_ROWS;
        if (i0 + 3 < N_ROWS) {
            *(float4*)&yp[i0] = v;
        } else {
            if (i0 + 0 < N_ROWS) yp[i0 + 0] = v.x;
            if (i0 + 1 < N_ROWS) yp[i0 + 1] = v.y;
            if (i0 + 2 < N_ROWS) yp[i0 + 2] = v.z;
            if (i0 + 3 < N_ROWS) yp[i0 + 3] = v.w;
        }
    }
}

// ---------------- overflow cleanup (expected ~0 entries) ----------------

__global__ void cleanup_kernel(const int* __restrict__ of_count,
                               const int4* __restrict__ of_list,
                               const float* __restrict__ x, float* __restrict__ y) {
    int n = *of_count;
    if (n > OF_CAP) n = OF_CAP;
    const int total = n * 64;
    for (int t = blockIdx.x * blockDim.x + threadIdx.x; t < total;
         t += gridDim.x * blockDim.x) {
        const int e = t >> 6, bc = t & 63;
        const int4 E = of_list[e];
        atomicAdd(&y[(size_t)bc * N_ROWS + E.x],
                  __int_as_float(E.z) * x[(size_t)bc * N_IN_SZ + E.y]);
    }
}

// ---------------- last-resort atomic COO ----------------

__global__ void regrid_coo_kernel(const float* __restrict__ x, const float* __restrict__ S,
                                  const int* __restrict__ rows, const int* __restrict__ cols,
                                  float* __restrict__ y, int nnz) {
    const int bc = blockIdx.y;
    const float* __restrict__ xp = x + (size_t)bc * N_IN_SZ;
    float* __restrict__ yp = y + (size_t)bc * N_ROWS;
    int k = blockIdx.x * blockDim.x + threadIdx.x;
    const int stride = gridDim.x * blockDim.x;
    for (; k < nnz; k += stride) {
        atomicAdd(&yp[rows[k]], S[k] * xp[cols[k]]);
    }
}

extern "C" void kernel_launch(void* const* d_in, const int* in_sizes, int n_in,
                              void* d_out, int out_size, void* d_ws, size_t ws_size,
                              hipStream_t stream) {
    const float* x    = (const float*)d_in[0];
    const float* S    = (const float*)d_in[1];
    const int*   rows = (const int*)d_in[2];
    const int*   cols = (const int*)d_in[3];
    float*       y    = (float*)d_out;
    const int nnz = in_sizes[1];

    // Workspace layout (256B-aligned chunks)
    const size_t SZ_CURSOR = ((size_t)N_ROWS * 4 + 255) & ~255ULL;             // 1.04 MB
    const size_t SZ_OFCNT  = 256;
    const size_t SZ_OFLIST = ((size_t)OF_CAP * 16 + 255) & ~255ULL;            // 64 KB
    const size_t SZ_EPAD   = ((size_t)N_ROWS * ROW_CAP * 8 + 255) & ~255ULL;   // 33.3 MB
    const size_t SZ_XT     = ((size_t)N_IN_SZ * BC * 2 + 255) & ~255ULL;       // 133 MB
    const size_t NEED = SZ_CURSOR + SZ_OFCNT + SZ_OFLIST + SZ_EPAD + SZ_XT;

    if (ws_size < NEED) {
        hipMemsetAsync(d_out, 0, (size_t)out_size * sizeof(float), stream);
        dim3 grid(1024, BC, 1);
        regrid_coo_kernel<<<grid, 256, 0, stream>>>(x, S, rows, cols, y, nnz);
        return;
    }

    char* w = (char*)d_ws;
    int*  cursor   = (int*)(w);
    int*  of_count = (int*)(w + SZ_CURSOR);
    int4* of_list  = (int4*)(w + SZ_CURSOR + SZ_OFCNT);
    int2* epad     = (int2*)(w + SZ_CURSOR + SZ_OFCNT + SZ_OFLIST);
    __hip_bfloat16* xt = (__hip_bfloat16*)(w + SZ_CURSOR + SZ_OFCNT + SZ_OFLIST + SZ_EPAD);

    // zero cursors + overflow count in one memset (contiguous)
    hipMemsetAsync(cursor, 0, SZ_CURSOR + SZ_OFCNT, stream);

    const int tBlocks = (N_IN_SZ + 63) / 64;          // 16,223 transpose tiles
    const int nBlocks = ((tBlocks + 4096) / 4) * 5;   // ~1/5 scatter, rest transpose
    prep_kernel<<<nBlocks, 256, 0, stream>>>(x, rows, cols, S, cursor, epad,
                                             of_count, of_list, xt, nnz);

    const int gBlocks = (N_ROWS + 63) / 64;           // 4,062
    gather_kernel<<<gBlocks, 256, 0, stream>>>(xt, cursor, epad, y);

    cleanup_kernel<<<16, 256, 0, stream>>>(of_count, of_list, x, y);
}